// Round 1
// baseline (10670.969 us; speedup 1.0000x reference)
//
#include <hip/hip_runtime.h>
#include <math.h>

#define B 8
#define C 512
#define L 2048

// ---------------------------------------------------------------------------
// Kernel 1: QKV projection.  O[b] = W (C x C) @ X[b] (C x L) + bias
// grid: (L/64, C/64, 3*B), block: 256 threads, 64x64 tile, BK=16, 4x4/thread
// ---------------------------------------------------------------------------
__global__ __launch_bounds__(256) void qkv_gemm(
    const float* __restrict__ x,
    const float* __restrict__ Wq, const float* __restrict__ bq,
    const float* __restrict__ Wk, const float* __restrict__ bk,
    const float* __restrict__ Wv, const float* __restrict__ bv,
    float* __restrict__ qo, float* __restrict__ ko, float* __restrict__ vo)
{
    const int which = blockIdx.z % 3;
    const int b     = blockIdx.z / 3;
    const float* W    = (which == 0) ? Wq : (which == 1) ? Wk : Wv;
    const float* bias = (which == 0) ? bq : (which == 1) ? bk : bv;
    float* O = ((which == 0) ? qo : (which == 1) ? ko : vo) + (size_t)b * C * L;
    const float* X = x + (size_t)b * C * L;

    const int m0 = blockIdx.y * 64;   // output-channel tile
    const int n0 = blockIdx.x * 64;   // position tile

    __shared__ float As[16][68];      // [k][m], padded rows (272 B, 16B-aligned)
    __shared__ float Bs[16][68];      // [k][n]

    const int t  = threadIdx.x;
    const int tn = t & 15;            // 16 col groups of 4
    const int tm = t >> 4;            // 16 row groups of 4
    float acc[4][4] = {};

    const int am  = t >> 2;           // A tile: row within tile (0..63)
    const int ak  = (t & 3) * 4;      // A tile: k offset {0,4,8,12}
    const int bk_ = t >> 4;           // B tile: k row (0..15)
    const int bn  = (t & 15) * 4;     // B tile: col offset

    for (int kk = 0; kk < C; kk += 16) {
        float4 a4 = *(const float4*)(W + (size_t)(m0 + am) * C + kk + ak);
        float4 b4 = *(const float4*)(X + (size_t)(kk + bk_) * L + n0 + bn);
        __syncthreads();              // previous iteration done reading LDS
        As[ak + 0][am] = a4.x;
        As[ak + 1][am] = a4.y;
        As[ak + 2][am] = a4.z;
        As[ak + 3][am] = a4.w;
        *(float4*)&Bs[bk_][bn] = b4;
        __syncthreads();
#pragma unroll
        for (int kc = 0; kc < 16; ++kc) {
            float4 av  = *(const float4*)&As[kc][tm * 4];
            float4 bv4 = *(const float4*)&Bs[kc][tn * 4];
            float aa[4] = {av.x, av.y, av.z, av.w};
            float bb[4] = {bv4.x, bv4.y, bv4.z, bv4.w};
#pragma unroll
            for (int i = 0; i < 4; ++i)
#pragma unroll
                for (int j = 0; j < 4; ++j)
                    acc[i][j] += aa[i] * bb[j];
        }
    }
#pragma unroll
    for (int i = 0; i < 4; ++i) {
        float bi = bias[m0 + tm * 4 + i];
        float4 o;
        o.x = acc[i][0] + bi;
        o.y = acc[i][1] + bi;
        o.z = acc[i][2] + bi;
        o.w = acc[i][3] + bi;
        *(float4*)(O + (size_t)(m0 + tm * 4 + i) * L + n0 + tn * 4) = o;
    }
}

// ---------------------------------------------------------------------------
// Kernel 2: fused flash-style attention, fp32.
// One block per (batch, 16-query tile). Online softmax over 64-key chunks.
// Thread layout (256 threads): qq = t>>4 (query 0..15), mg = t&15.
//   scores phase:     thread computes scores for (qq, m0 + mg*4 .. +3)
//   accumulate phase: thread owns out channels c = mg + 16*j, j=0..31
// ---------------------------------------------------------------------------
__global__ __launch_bounds__(256) void attn(
    const float* __restrict__ q, const float* __restrict__ k,
    const float* __restrict__ v, float* __restrict__ out)
{
    const int b  = blockIdx.y;
    const int l0 = blockIdx.x * 16;
    const int t  = threadIdx.x;
    const int qq = t >> 4;
    const int mg = t & 15;

    __shared__ float q_s[16][513];    // +1 pad: q_s[q][c] broadcasts hit 16 banks otherwise
    __shared__ float s_s[16][65];     // probabilities for current chunk
    __shared__ float cmax[16];
    __shared__ float m_state[16], l_state[16], alpha_s[16];

    const float* Q = q + (size_t)b * C * L;
    const float* K = k + (size_t)b * C * L;
    const float* V = v + (size_t)b * C * L;

    // stage Q tile: q_s[qi][c] = Q[c][l0+qi]
    for (int e = t; e < 16 * C; e += 256) {
        int qi = e & 15, c = e >> 4;
        q_s[qi][c] = Q[(size_t)c * L + l0 + qi];
    }
    if (t < 16) { m_state[t] = -INFINITY; l_state[t] = 0.0f; }
    float acc[32];
#pragma unroll
    for (int j = 0; j < 32; ++j) acc[j] = 0.0f;
    __syncthreads();

    const float scale = 0.044194173824159216f;   // 1/sqrt(512)

    for (int m0 = 0; m0 < L; m0 += 64) {
        // ---- phase a: scores (registers only, no LDS writes) ----
        float4 s4 = make_float4(0.f, 0.f, 0.f, 0.f);
        const float* kp = K + m0 + mg * 4;
        for (int c = 0; c < C; ++c) {
            float4 k4 = *(const float4*)(kp);
            kp += L;
            float qv = q_s[qq][c];
            s4.x += qv * k4.x; s4.y += qv * k4.y;
            s4.z += qv * k4.z; s4.w += qv * k4.w;
        }
        s4.x *= scale; s4.y *= scale; s4.z *= scale; s4.w *= scale;

        __syncthreads();   // previous accumulate done reading s_s / alpha_s

        // ---- phase b: chunk max (read m_state BEFORE it is rewritten) ----
        float mold = m_state[qq];
        float lmax = fmaxf(fmaxf(s4.x, s4.y), fmaxf(s4.z, s4.w));
#pragma unroll
        for (int d = 1; d < 16; d <<= 1)
            lmax = fmaxf(lmax, __shfl_xor(lmax, d, 64));
        if (mg == 0) cmax[qq] = lmax;
        __syncthreads();

        // ---- phase c: exp, row sum, state update ----
        float mnew = fmaxf(mold, cmax[qq]);
        float4 p4;
        p4.x = __expf(s4.x - mnew);
        p4.y = __expf(s4.y - mnew);
        p4.z = __expf(s4.z - mnew);
        p4.w = __expf(s4.w - mnew);
        s_s[qq][mg * 4 + 0] = p4.x;
        s_s[qq][mg * 4 + 1] = p4.y;
        s_s[qq][mg * 4 + 2] = p4.z;
        s_s[qq][mg * 4 + 3] = p4.w;
        float lsum = p4.x + p4.y + p4.z + p4.w;
#pragma unroll
        for (int d = 1; d < 16; d <<= 1)
            lsum += __shfl_xor(lsum, d, 64);
        if (mg == 0) {
            float alpha = __expf(mold - mnew);
            l_state[qq] = l_state[qq] * alpha + lsum;
            m_state[qq] = mnew;
            alpha_s[qq] = alpha;
        }
        __syncthreads();

        // ---- phase d: accumulate PV ----
        float alpha = alpha_s[qq];
#pragma unroll
        for (int j = 0; j < 32; ++j) acc[j] *= alpha;
        const float* vp = V + m0 + (size_t)mg * L;
        for (int m4 = 0; m4 < 16; ++m4) {
            float p0 = s_s[qq][m4 * 4 + 0];
            float p1 = s_s[qq][m4 * 4 + 1];
            float p2 = s_s[qq][m4 * 4 + 2];
            float p3 = s_s[qq][m4 * 4 + 3];
            const float* vq = vp + m4 * 4;
#pragma unroll
            for (int j = 0; j < 32; ++j) {
                float4 v4 = *(const float4*)(vq + (size_t)j * 16 * L);
                acc[j] += p0 * v4.x + p1 * v4.y + p2 * v4.z + p3 * v4.w;
            }
        }
    }

    const float linv = 1.0f / l_state[qq];
    float* Ob = out + (size_t)b * C * L;
#pragma unroll
    for (int j = 0; j < 32; ++j) {
        int c = mg + 16 * j;
        Ob[(size_t)c * L + l0 + qq] = acc[j] * linv;
    }
}

extern "C" void kernel_launch(void* const* d_in, const int* in_sizes, int n_in,
                              void* d_out, int out_size, void* d_ws, size_t ws_size,
                              hipStream_t stream) {
    const float* x  = (const float*)d_in[0];
    const float* Wq = (const float*)d_in[1];
    const float* bq = (const float*)d_in[2];
    const float* Wk = (const float*)d_in[3];
    const float* bk = (const float*)d_in[4];
    const float* Wv = (const float*)d_in[5];
    const float* bv = (const float*)d_in[6];
    float* out = (float*)d_out;

    const size_t BCL = (size_t)B * C * L;
    float* q = (float*)d_ws;          // 33.5 MB
    float* k = q + BCL;               // 33.5 MB
    float* v = k + BCL;               // 33.5 MB  (total 100.7 MB of ws)

    qkv_gemm<<<dim3(L / 64, C / 64, 3 * B), 256, 0, stream>>>(
        x, Wq, bq, Wk, bk, Wv, bv, q, k, v);
    attn<<<dim3(L / 16, B), 256, 0, stream>>>(q, k, v, out);
}

// Round 2
// 592.622 us; speedup vs baseline: 18.0064x; 18.0064x over previous
//
#include <hip/hip_runtime.h>
#include <hip/hip_bf16.h>
#include <math.h>

#define B 8
#define C 512
#define L 2048

using bf16x8 = __bf16 __attribute__((ext_vector_type(8)));
using f32x4  = float __attribute__((ext_vector_type(4)));

#define MFMA(a, b, c) __builtin_amdgcn_mfma_f32_16x16x32_bf16((a), (b), (c), 0, 0, 0)

__device__ __forceinline__ unsigned short f2bf(float f) {
    __hip_bfloat16 h = __float2bfloat16(f);   // RNE
    return *reinterpret_cast<unsigned short*>(&h);
}

// ---------------------------------------------------------------------------
// Kernel 0a: x [B][C][L] fp32  ->  xt [B][L][C] bf16  (32x32 LDS transpose)
// ---------------------------------------------------------------------------
__global__ __launch_bounds__(256) void xpose_cvt(
    const float* __restrict__ x, unsigned short* __restrict__ xt)
{
    __shared__ float tile[32][33];
    const int b = blockIdx.z, l0 = blockIdx.x * 32, c0 = blockIdx.y * 32;
    const int tx = threadIdx.x & 31, ty = threadIdx.x >> 5;
    const float* xb = x + (size_t)b * C * L;
#pragma unroll
    for (int k = 0; k < 4; ++k)
        tile[ty + 8 * k][tx] = xb[(size_t)(c0 + ty + 8 * k) * L + l0 + tx];
    __syncthreads();
    unsigned short* xtb = xt + (size_t)b * L * C;
#pragma unroll
    for (int k = 0; k < 4; ++k)
        xtb[(size_t)(l0 + ty + 8 * k) * C + c0 + tx] = f2bf(tile[tx][ty + 8 * k]);
}

// ---------------------------------------------------------------------------
// Kernel 0b: Wq|Wk|Wv fp32 -> contiguous bf16 (row-major, unchanged layout)
// ---------------------------------------------------------------------------
__global__ __launch_bounds__(256) void wcvt(
    const float* __restrict__ Wq, const float* __restrict__ Wk,
    const float* __restrict__ Wv, unsigned short* __restrict__ o)
{
    const int i = (blockIdx.x * 256 + threadIdx.x) * 4;   // 3*C*C total
    const int which = i >> 18;                            // C*C = 2^18
    const int off = i & 0x3FFFF;
    const float* src = (which == 0) ? Wq : (which == 1) ? Wk : Wv;
    float4 v = *(const float4*)(src + off);
    union { unsigned short h[4]; uint2 u; } pk;
    pk.h[0] = f2bf(v.x); pk.h[1] = f2bf(v.y); pk.h[2] = f2bf(v.z); pk.h[3] = f2bf(v.w);
    *(uint2*)(o + i) = pk.u;
}

// ---------------------------------------------------------------------------
// Kernel 1: QKV projection, MFMA GEMM-NT:  D[m][n] = sum_k A[m][k] * Bn[n][k]
//   which 0/1 (Q,K): A=xt[b] (2048xK), Bn=W (512xK), out=[L][C], bias over n
//   which 2   (V):   A=Wv   (512xK),  Bn=xt[b],     out=[C][L], bias over m
// 64x64 tile / block, 4 waves in 2x2, 32x32 per wave, direct-global fragments.
// ---------------------------------------------------------------------------
__global__ __launch_bounds__(256) void qkv_mfma(
    const unsigned short* __restrict__ xt, const unsigned short* __restrict__ Wb,
    const float* __restrict__ bq, const float* __restrict__ bk,
    const float* __restrict__ bv,
    unsigned short* __restrict__ Qt, unsigned short* __restrict__ Kt,
    unsigned short* __restrict__ Vv)
{
    const int which = blockIdx.z % 3;
    const int b     = blockIdx.z / 3;
    const unsigned short* xtb = xt + (size_t)b * L * C;

    const unsigned short *A, *Bn;
    unsigned short* Out;
    const float* bias;
    int pitch, m0, n0, biasaxis;
    if (which < 2) {
        A = xtb; Bn = Wb + (size_t)which * C * C; bias = which ? bk : bq;
        Out = (which ? Kt : Qt) + (size_t)b * L * C;
        pitch = C; biasaxis = 1;
        m0 = blockIdx.x * 64; n0 = blockIdx.y * 64;      // M=2048, N=512
    } else {
        A = Wb + (size_t)2 * C * C; Bn = xtb; bias = bv;
        Out = Vv + (size_t)b * C * L;
        pitch = L; biasaxis = 0;
        m0 = blockIdx.y * 64; n0 = blockIdx.x * 64;      // M=512, N=2048
    }

    const int t = threadIdx.x, w = t >> 6, ll = t & 15, quad = (t >> 4) & 3;
    const int mo = m0 + (w & 1) * 32;
    const int no = n0 + (w >> 1) * 32;

    const unsigned short* Ap = A  + (size_t)(mo + ll) * C + quad * 8;
    const unsigned short* Bp = Bn + (size_t)(no + ll) * C + quad * 8;

    f32x4 acc[2][2];
#pragma unroll
    for (int i = 0; i < 2; ++i)
#pragma unroll
        for (int j = 0; j < 2; ++j) acc[i][j] = (f32x4){0.f, 0.f, 0.f, 0.f};

#pragma unroll 2
    for (int k0 = 0; k0 < C; k0 += 32) {
        bf16x8 a0 = *(const bf16x8*)(Ap + k0);
        bf16x8 a1 = *(const bf16x8*)(Ap + (size_t)16 * C + k0);
        bf16x8 b0 = *(const bf16x8*)(Bp + k0);
        bf16x8 b1 = *(const bf16x8*)(Bp + (size_t)16 * C + k0);
        acc[0][0] = MFMA(a0, b0, acc[0][0]);
        acc[0][1] = MFMA(a0, b1, acc[0][1]);
        acc[1][0] = MFMA(a1, b0, acc[1][0]);
        acc[1][1] = MFMA(a1, b1, acc[1][1]);
    }

#pragma unroll
    for (int mi = 0; mi < 2; ++mi)
#pragma unroll
        for (int ni = 0; ni < 2; ++ni)
#pragma unroll
            for (int r = 0; r < 4; ++r) {
                int row = mo + mi * 16 + quad * 4 + r;
                int col = no + ni * 16 + ll;
                float v = acc[mi][ni][r] + (biasaxis ? bias[col] : bias[row]);
                Out[(size_t)row * pitch + col] = f2bf(v);
            }
}

// ---------------------------------------------------------------------------
// Kernel 2: fused flash attention, bf16 MFMA.
// Block: 256 thr (4 waves), 32-query tile, 64-key chunks.
//   P1: wave w computes S[32 q][16 keys] (Q frags in regs, K frags from global)
//   P2: 256-thread softmax (8 thr/row), P -> LDS bf16 in A-operand layout
//   P3: wave w accumulates O^T[32 q][128 ch] (V frags from global)
// Epilogue: transpose O through LDS for 128B-contiguous out[C][L] stores.
// ---------------------------------------------------------------------------
__global__ __launch_bounds__(256, 2) void attn_mfma(
    const unsigned short* __restrict__ Qt, const unsigned short* __restrict__ Kt,
    const unsigned short* __restrict__ Vv, float* __restrict__ out)
{
    __shared__ float s_s[32][68];            // scaled scores (pad: +4, 16B rows)
    __shared__ unsigned short p_s[32][72];   // probs bf16, A-layout (144B rows)
    __shared__ float o_s[32][260];           // epilogue transpose (half channels)
    __shared__ float m_state[32], l_state[32], alpha_s[32];

    const int b = blockIdx.y, l0 = blockIdx.x * 32;
    const int t = threadIdx.x, w = t >> 6, ll = t & 15, quad = (t >> 4) & 3;
    const unsigned short* Qb = Qt + (size_t)b * L * C;
    const unsigned short* Kb = Kt + (size_t)b * L * C;
    const unsigned short* Vb = Vv + (size_t)b * C * L;

    // Q fragments in registers: A[m=ll][k], 2 m-subtiles x 16 k-steps
    bf16x8 qf[2][16];
#pragma unroll
    for (int mt = 0; mt < 2; ++mt) {
        const unsigned short* qp = Qb + (size_t)(l0 + mt * 16 + ll) * C + quad * 8;
#pragma unroll
        for (int kk = 0; kk < 16; ++kk) qf[mt][kk] = *(const bf16x8*)(qp + kk * 32);
    }
    if (t < 32) { m_state[t] = -INFINITY; l_state[t] = 0.f; }

    f32x4 acc_o[2][8];
#pragma unroll
    for (int mt = 0; mt < 2; ++mt)
#pragma unroll
        for (int nt = 0; nt < 8; ++nt) acc_o[mt][nt] = (f32x4){0.f, 0.f, 0.f, 0.f};

    const float scale = 0.044194173824159216f;   // 1/sqrt(512)
    const int row2 = t >> 3, cg = t & 7;         // softmax mapping: 8 thr/row

    for (int kc = 0; kc < L; kc += 64) {
        // ---- P1: scores ----
        f32x4 s0 = (f32x4){0.f, 0.f, 0.f, 0.f};
        f32x4 s1 = (f32x4){0.f, 0.f, 0.f, 0.f};
        const unsigned short* kp = Kb + (size_t)(kc + w * 16 + ll) * C + quad * 8;
#pragma unroll
        for (int kk = 0; kk < 16; ++kk) {
            bf16x8 bf = *(const bf16x8*)(kp + kk * 32);
            s0 = MFMA(qf[0][kk], bf, s0);
            s1 = MFMA(qf[1][kk], bf, s1);
        }
#pragma unroll
        for (int r = 0; r < 4; ++r) {
            s_s[quad * 4 + r][w * 16 + ll]      = s0[r] * scale;
            s_s[16 + quad * 4 + r][w * 16 + ll] = s1[r] * scale;
        }
        __syncthreads();

        // ---- P2: online softmax (rows 0..31, 8 threads per row) ----
        float sv[8];
        *(float4*)&sv[0] = *(const float4*)&s_s[row2][cg * 8];
        *(float4*)&sv[4] = *(const float4*)&s_s[row2][cg * 8 + 4];
        float mx = sv[0];
#pragma unroll
        for (int j = 1; j < 8; ++j) mx = fmaxf(mx, sv[j]);
#pragma unroll
        for (int d = 1; d < 8; d <<= 1) mx = fmaxf(mx, __shfl_xor(mx, d));
        const float mold = m_state[row2];
        const float mnew = fmaxf(mold, mx);
        union { unsigned short h[8]; uint4 u; } pk;
        float psum = 0.f;
#pragma unroll
        for (int j = 0; j < 8; ++j) {
            float p = __expf(sv[j] - mnew);
            psum += p;
            pk.h[j] = f2bf(p);
        }
        *(uint4*)&p_s[row2][cg * 8] = pk.u;
#pragma unroll
        for (int d = 1; d < 8; d <<= 1) psum += __shfl_xor(psum, d);
        if (cg == 0) {
            float alpha = __expf(mold - mnew);
            l_state[row2] = l_state[row2] * alpha + psum;
            m_state[row2] = mnew;
            alpha_s[row2] = alpha;
        }
        __syncthreads();

        // ---- P3: PV accumulate (wave w owns channels w*128..+127) ----
        float al[2][4];
#pragma unroll
        for (int mt = 0; mt < 2; ++mt)
#pragma unroll
            for (int r = 0; r < 4; ++r) al[mt][r] = alpha_s[mt * 16 + quad * 4 + r];
#pragma unroll
        for (int mt = 0; mt < 2; ++mt)
#pragma unroll
            for (int nt = 0; nt < 8; ++nt)
#pragma unroll
                for (int r = 0; r < 4; ++r) acc_o[mt][nt][r] *= al[mt][r];

#pragma unroll
        for (int k2 = 0; k2 < 2; ++k2) {
            bf16x8 a0 = *(const bf16x8*)&p_s[ll][k2 * 32 + quad * 8];
            bf16x8 a1 = *(const bf16x8*)&p_s[16 + ll][k2 * 32 + quad * 8];
            const unsigned short* vp =
                Vb + (size_t)(w * 128 + ll) * L + kc + k2 * 32 + quad * 8;
#pragma unroll
            for (int nt = 0; nt < 8; ++nt) {
                bf16x8 bv8 = *(const bf16x8*)(vp + (size_t)nt * 16 * L);
                acc_o[0][nt] = MFMA(a0, bv8, acc_o[0][nt]);
                acc_o[1][nt] = MFMA(a1, bv8, acc_o[1][nt]);
            }
        }
        // no barrier needed: next P1 writes s_s only; post-P1 barrier orders p_s
    }

    // ---- epilogue: O^T frags -> LDS transpose -> out[C][L] ----
    float linv[2][4];
#pragma unroll
    for (int mt = 0; mt < 2; ++mt)
#pragma unroll
        for (int r = 0; r < 4; ++r)
            linv[mt][r] = 1.f / l_state[mt * 16 + quad * 4 + r];

    float* Ob = out + (size_t)b * C * L;
#pragma unroll
    for (int h = 0; h < 2; ++h) {
        __syncthreads();
        if ((w >> 1) == h) {
#pragma unroll
            for (int mt = 0; mt < 2; ++mt)
#pragma unroll
                for (int nt = 0; nt < 8; ++nt)
#pragma unroll
                    for (int r = 0; r < 4; ++r)
                        o_s[mt * 16 + quad * 4 + r][(w & 1) * 128 + nt * 16 + ll] =
                            acc_o[mt][nt][r] * linv[mt][r];
        }
        __syncthreads();
        const int c = t;
        float* op = Ob + (size_t)(h * 256 + c) * L + l0;
#pragma unroll
        for (int qg = 0; qg < 8; ++qg) {
            float4 v4 = make_float4(o_s[qg * 4 + 0][c], o_s[qg * 4 + 1][c],
                                    o_s[qg * 4 + 2][c], o_s[qg * 4 + 3][c]);
            *(float4*)(op + qg * 4) = v4;
        }
    }
}

extern "C" void kernel_launch(void* const* d_in, const int* in_sizes, int n_in,
                              void* d_out, int out_size, void* d_ws, size_t ws_size,
                              hipStream_t stream) {
    const float* x  = (const float*)d_in[0];
    const float* Wq = (const float*)d_in[1];
    const float* bq = (const float*)d_in[2];
    const float* Wk = (const float*)d_in[3];
    const float* bk = (const float*)d_in[4];
    const float* Wv = (const float*)d_in[5];
    const float* bv = (const float*)d_in[6];
    float* out = (float*)d_out;

    const size_t BCL = (size_t)B * C * L;          // 8.39M elems
    unsigned short* xt  = (unsigned short*)d_ws;   // [B][L][C] bf16, 16.8 MB
    unsigned short* Qt  = xt + BCL;                // [B][L][C]
    unsigned short* Kt  = Qt + BCL;                // [B][L][C]
    unsigned short* Vv  = Kt + BCL;                // [B][C][L]
    unsigned short* Wb  = Vv + BCL;                // 3 x [C][C] bf16, 1.5 MB

    xpose_cvt<<<dim3(L / 32, C / 32, B), 256, 0, stream>>>(x, xt);
    wcvt<<<dim3(3 * C * C / 1024), 256, 0, stream>>>(Wq, Wk, Wv, Wb);
    qkv_mfma<<<dim3(32, 8, 3 * B), 256, 0, stream>>>(xt, Wb, bq, bk, bv, Qt, Kt, Vv);
    attn_mfma<<<dim3(L / 32, B), 256, 0, stream>>>(Qt, Kt, Vv, out);
}

// Round 3
// 300.086 us; speedup vs baseline: 35.5597x; 1.9748x over previous
//
#include <hip/hip_runtime.h>
#include <hip/hip_bf16.h>
#include <math.h>

#define B 8
#define C 512
#define L 2048

using bf16x8 = __bf16 __attribute__((ext_vector_type(8)));
using f32x4  = float __attribute__((ext_vector_type(4)));

#define MFMA(a, b, c) __builtin_amdgcn_mfma_f32_16x16x32_bf16((a), (b), (c), 0, 0, 0)
#define SCALE 0.044194173824159216f   /* 1/sqrt(512) */

__device__ __forceinline__ unsigned short f2bf(float f) {
    __hip_bfloat16 h = __float2bfloat16(f);   // RNE
    return *reinterpret_cast<unsigned short*>(&h);
}
__device__ __forceinline__ float bf2f(unsigned short h) {
    unsigned int u = (unsigned int)h << 16;
    float f; __builtin_memcpy(&f, &u, 4); return f;
}
// async global->LDS, 16B/lane. lds dest must be wave-uniform base (+lane*16 in HW).
__device__ __forceinline__ void load_lds16(const unsigned short* g, unsigned short* l) {
    __builtin_amdgcn_global_load_lds(
        (const __attribute__((address_space(1))) unsigned int*)g,
        (__attribute__((address_space(3))) unsigned int*)l, 16, 0, 0);
}

// ---------------------------------------------------------------------------
// m97-style GEMM-NT core: D[128m][128n] = A[128][K] * B[128][K]^T (+ epilogue)
// lda = ldb = KDIM. 256 thr = 4 waves (2x2 of 64x64), BK=32, LDS-staged.
// MODE 0: +bias[col], bf16 out   (QKV q/k)
// MODE 1: +bias[row], bf16 out   (QKV v)
// MODE 2: exp(d*SCALE-12), bf16  (scores->P)
// MODE 3: *linv[col], f32 out    (PV)
// ---------------------------------------------------------------------------
template<int MODE, int KDIM>
__device__ __forceinline__ void gemm_core(
    const unsigned short* __restrict__ A,   // pre-offset to tile row m0
    const unsigned short* __restrict__ Bm,  // pre-offset to tile row n0
    unsigned short* As, unsigned short* Bs, // [128*32] each
    void* __restrict__ OutV, int ldo,       // pre-offset to (m0, n0)
    const float* __restrict__ ep)           // pre-offset bias/linv (or null)
{
    const int t = threadIdx.x;
    const int wave = t >> 6, lane = t & 63;
    const int ll = t & 15, quad = (t >> 4) & 3;
    const int lr = lane >> 2, chunk = lane & 3;
    const int wm = (wave & 1) * 64, wn = (wave >> 1) * 64;

    // staging: wave w fills rows [w*32, w*32+32) of both tiles; 16B/lane
    const unsigned short* gA0 = A  + (size_t)(wave * 32 + lr) * KDIM + chunk * 8;
    const unsigned short* gB0 = Bm + (size_t)(wave * 32 + lr) * KDIM + chunk * 8;
    unsigned short* lA0 = As + (wave * 32) * 32;        // wave-uniform
    unsigned short* lA1 = As + (wave * 32 + 16) * 32;
    unsigned short* lB0 = Bs + (wave * 32) * 32;
    unsigned short* lB1 = Bs + (wave * 32 + 16) * 32;

    f32x4 acc[4][4];
#pragma unroll
    for (int i = 0; i < 4; ++i)
#pragma unroll
        for (int j = 0; j < 4; ++j) acc[i][j] = (f32x4){0.f, 0.f, 0.f, 0.f};

#pragma unroll 1
    for (int k0 = 0; k0 < KDIM; k0 += 32) {
        __syncthreads();                       // prev compute done reading LDS
        load_lds16(gA0 + k0, lA0);
        load_lds16(gA0 + (size_t)16 * KDIM + k0, lA1);
        load_lds16(gB0 + k0, lB0);
        load_lds16(gB0 + (size_t)16 * KDIM + k0, lB1);
        __syncthreads();                       // staging visible (vmcnt drain)

        bf16x8 af[4], bf[4];
#pragma unroll
        for (int mi = 0; mi < 4; ++mi)
            af[mi] = *(const bf16x8*)&As[(wm + mi * 16 + ll) * 32 + quad * 8];
#pragma unroll
        for (int ni = 0; ni < 4; ++ni)
            bf[ni] = *(const bf16x8*)&Bs[(wn + ni * 16 + ll) * 32 + quad * 8];
#pragma unroll
        for (int mi = 0; mi < 4; ++mi)
#pragma unroll
            for (int ni = 0; ni < 4; ++ni)
                acc[mi][ni] = MFMA(af[mi], bf[ni], acc[mi][ni]);
    }

#pragma unroll
    for (int mi = 0; mi < 4; ++mi)
#pragma unroll
        for (int ni = 0; ni < 4; ++ni) {
            const int col = wn + ni * 16 + ll;
            float epc = (MODE == 0 || MODE == 3) ? ep[col] : 0.f;
#pragma unroll
            for (int r = 0; r < 4; ++r) {
                const int row = wm + mi * 16 + quad * 4 + r;
                float v = acc[mi][ni][r];
                if (MODE == 0)      v += epc;
                else if (MODE == 1) v += ep[row];
                else if (MODE == 2) v = __expf(v * SCALE - 12.f);
                else                v *= epc;
                if (MODE == 3)
                    ((float*)OutV)[(size_t)row * ldo + col] = v;
                else
                    ((unsigned short*)OutV)[(size_t)row * ldo + col] = f2bf(v);
            }
        }
}

// ---------------------------------------------------------------------------
// Kernel 0a: x [B][C][L] fp32 -> xt [B][L][C] bf16 (32x32 LDS transpose)
// ---------------------------------------------------------------------------
__global__ __launch_bounds__(256) void xpose_cvt(
    const float* __restrict__ x, unsigned short* __restrict__ xt)
{
    __shared__ float tile[32][33];
    const int b = blockIdx.z, l0 = blockIdx.x * 32, c0 = blockIdx.y * 32;
    const int tx = threadIdx.x & 31, ty = threadIdx.x >> 5;
    const float* xb = x + (size_t)b * C * L;
#pragma unroll
    for (int k = 0; k < 4; ++k)
        tile[ty + 8 * k][tx] = xb[(size_t)(c0 + ty + 8 * k) * L + l0 + tx];
    __syncthreads();
    unsigned short* xtb = xt + (size_t)b * L * C;
#pragma unroll
    for (int k = 0; k < 4; ++k)
        xtb[(size_t)(l0 + ty + 8 * k) * C + c0 + tx] = f2bf(tile[tx][ty + 8 * k]);
}

// ---------------------------------------------------------------------------
// Kernel 0b: Wq|Wk|Wv fp32 -> contiguous bf16
// ---------------------------------------------------------------------------
__global__ __launch_bounds__(256) void wcvt(
    const float* __restrict__ Wq, const float* __restrict__ Wk,
    const float* __restrict__ Wv, unsigned short* __restrict__ o)
{
    const int i = (blockIdx.x * 256 + threadIdx.x) * 4;
    const int which = i >> 18;                            // C*C = 2^18
    const int off = i & 0x3FFFF;
    const float* src = (which == 0) ? Wq : (which == 1) ? Wk : Wv;
    float4 v = *(const float4*)(src + off);
    union { unsigned short h[4]; uint2 u; } pk;
    pk.h[0] = f2bf(v.x); pk.h[1] = f2bf(v.y); pk.h[2] = f2bf(v.z); pk.h[3] = f2bf(v.w);
    *(uint2*)(o + i) = pk.u;
}

// ---------------------------------------------------------------------------
// Kernel 1: QKV projection (staged MFMA GEMM-NT)
//   which 0/1: Q/K = xt @ W^T -> [L][C] bf16 (bias over col)
//   which 2  : V   = Wv @ xt^T -> [C][L] bf16 (bias over row)
// ---------------------------------------------------------------------------
__global__ __launch_bounds__(256) void qkv_gemm(
    const unsigned short* __restrict__ xt, const unsigned short* __restrict__ Wb,
    const float* __restrict__ bq, const float* __restrict__ bk,
    const float* __restrict__ bv,
    unsigned short* __restrict__ Qt, unsigned short* __restrict__ Kt,
    unsigned short* __restrict__ Vv)
{
    __shared__ unsigned short As[128 * 32], Bs[128 * 32];
    const int which = blockIdx.z >> 3, b = blockIdx.z & 7;
    const unsigned short* xtb = xt + (size_t)b * L * C;
    if (which < 2) {
        const int m0 = blockIdx.x * 128, n0 = blockIdx.y * 128;  // M=L, N=C
        const unsigned short* A  = xtb + (size_t)m0 * C;
        const unsigned short* Bm = Wb + (size_t)which * C * C + (size_t)n0 * C;
        unsigned short* Out = (which ? Kt : Qt) + (size_t)b * L * C
                              + (size_t)m0 * C + n0;
        gemm_core<0, C>(A, Bm, As, Bs, Out, C, (which ? bk : bq) + n0);
    } else {
        const int m0 = blockIdx.y * 128, n0 = blockIdx.x * 128;  // M=C, N=L
        const unsigned short* A  = Wb + (size_t)2 * C * C + (size_t)m0 * C;
        const unsigned short* Bm = xtb + (size_t)n0 * C;
        unsigned short* Out = Vv + (size_t)b * C * L + (size_t)m0 * L + n0;
        gemm_core<1, C>(A, Bm, As, Bs, Out, L, bv + m0);
    }
}

// ---------------------------------------------------------------------------
// Kernel 2: P = exp(Q K^T * scale - 12), one lq-half (1024 rows) per launch
// ---------------------------------------------------------------------------
__global__ __launch_bounds__(256) void sc_exp(
    const unsigned short* __restrict__ Qh, const unsigned short* __restrict__ Kt,
    unsigned short* __restrict__ Ph)
{
    __shared__ unsigned short As[128 * 32], Bs[128 * 32];
    const int b = blockIdx.z, m0 = blockIdx.x * 128, n0 = blockIdx.y * 128;
    const unsigned short* A  = Qh + (size_t)b * L * C + (size_t)m0 * C;
    const unsigned short* Bm = Kt + (size_t)b * L * C + (size_t)n0 * C;
    unsigned short* Out = Ph + (size_t)b * 1024 * L + (size_t)m0 * L + n0;
    gemm_core<2, C>(A, Bm, As, Bs, Out, L, nullptr);
}

// ---------------------------------------------------------------------------
// Kernel 3: linv[row] = 1 / sum_k P[row][k]   (one row per wave)
// ---------------------------------------------------------------------------
__global__ __launch_bounds__(256) void rowsum(
    const unsigned short* __restrict__ Ph, float* __restrict__ linv)
{
    const int row = blockIdx.x * 4 + (threadIdx.x >> 6);
    const int lane = threadIdx.x & 63;
    const unsigned short* p = Ph + (size_t)row * L + lane * 8;
    float s = 0.f;
#pragma unroll
    for (int j = 0; j < 4; ++j) {
        uint4 raw = *(const uint4*)(p + j * 512);
        const unsigned short* hp = (const unsigned short*)&raw;
#pragma unroll
        for (int e = 0; e < 8; ++e) s += bf2f(hp[e]);
    }
#pragma unroll
    for (int d = 1; d < 64; d <<= 1) s += __shfl_xor(s, d, 64);
    if (lane == 0) linv[row] = 1.0f / s;
}

// ---------------------------------------------------------------------------
// Kernel 4: O[:, half] = (V @ P^T) * linv[col]
// ---------------------------------------------------------------------------
__global__ __launch_bounds__(256) void pv_gemm(
    const unsigned short* __restrict__ Vv, const unsigned short* __restrict__ Ph,
    const float* __restrict__ linv, float* __restrict__ outh)
{
    __shared__ unsigned short As[128 * 32], Bs[128 * 32];
    const int b = blockIdx.z, m0 = blockIdx.x * 128, n0 = blockIdx.y * 128;
    const unsigned short* A  = Vv + (size_t)b * C * L + (size_t)m0 * L;
    const unsigned short* Bm = Ph + (size_t)b * 1024 * L + (size_t)n0 * L;
    float* Out = outh + (size_t)b * C * L + (size_t)m0 * L + n0;
    gemm_core<3, L>(A, Bm, As, Bs, Out, L, linv + (size_t)b * 1024 + n0);
}

extern "C" void kernel_launch(void* const* d_in, const int* in_sizes, int n_in,
                              void* d_out, int out_size, void* d_ws, size_t ws_size,
                              hipStream_t stream) {
    const float* x  = (const float*)d_in[0];
    const float* Wq = (const float*)d_in[1];
    const float* bq = (const float*)d_in[2];
    const float* Wk = (const float*)d_in[3];
    const float* bk = (const float*)d_in[4];
    const float* Wv = (const float*)d_in[5];
    const float* bv = (const float*)d_in[6];
    float* out = (float*)d_out;

    const size_t BCL = (size_t)B * C * L;                // 8.39M elems
    unsigned short* Qt = (unsigned short*)d_ws;          // [B][L][C] bf16
    unsigned short* Kt = Qt + BCL;                       // [B][L][C]
    unsigned short* Vv = Kt + BCL;                       // [B][C][L]
    unsigned short* xt = Vv + BCL;                       // [B][L][C] (dead after qkv)
    unsigned short* Ph = xt;                             // [B][1024][L] bf16, ALIASES xt
    unsigned short* Wb = Ph + (size_t)B * 1024 * L;      // 3x[C][C] bf16 (dead after qkv? NO:
                                                         //  placed beyond Ph? see note)
    // NOTE: Ph spans xt (8.39M shorts) + 8.39M more; Wb sits after Ph's end,
    // so Wb never overlaps xt/Qt/Kt/Vv and is only clobber-free: Wb is live
    // during qkv only, Ph is written only after qkv completes -> no conflict.
    float* linv = (float*)(Wb + (size_t)3 * C * C);      // [B*1024] f32
    // total ws: 3*16.78 + 33.55 + 1.57 + 0.03 MB = ~85.5 MB

    xpose_cvt<<<dim3(L / 32, C / 32, B), 256, 0, stream>>>(x, xt);
    wcvt<<<dim3(3 * C * C / 1024), 256, 0, stream>>>(Wq, Wk, Wv, Wb);
    qkv_gemm<<<dim3(16, 4, 24), 256, 0, stream>>>(xt, Wb, bq, bk, bv, Qt, Kt, Vv);

    for (int h = 0; h < 2; ++h) {
        sc_exp<<<dim3(8, 16, 8), 256, 0, stream>>>(Qt + (size_t)h * 1024 * C, Kt, Ph);
        rowsum<<<dim3(B * 1024 / 4), 256, 0, stream>>>(Ph, linv);
        pv_gemm<<<dim3(4, 8, 8), 256, 0, stream>>>(Vv, Ph, linv, out + (size_t)h * 1024);
    }
}

// Round 4
// 286.645 us; speedup vs baseline: 37.2272x; 1.0469x over previous
//
#include <hip/hip_runtime.h>
#include <hip/hip_bf16.h>
#include <math.h>

#define B 8
#define C 512
#define L 2048

using bf16x8 = __bf16 __attribute__((ext_vector_type(8)));
using f32x4  = float __attribute__((ext_vector_type(4)));

#define MFMA(a, b, c) __builtin_amdgcn_mfma_f32_16x16x32_bf16((a), (b), (c), 0, 0, 0)
#define SCALE 0.044194173824159216f   /* 1/sqrt(512) */

__device__ __forceinline__ unsigned short f2bf(float f) {
    __hip_bfloat16 h = __float2bfloat16(f);   // RNE
    return *reinterpret_cast<unsigned short*>(&h);
}
// async global->LDS, 16B/lane; LDS dest = wave-uniform base + lane*16
__device__ __forceinline__ void load_lds16(const unsigned short* g, unsigned short* l) {
    __builtin_amdgcn_global_load_lds(
        (const __attribute__((address_space(1))) unsigned int*)g,
        (__attribute__((address_space(3))) unsigned int*)l, 16, 0, 0);
}

// ---------------------------------------------------------------------------
// GEMM-NT core: D[TM m][128 n] = A[TM][K] * B[128][K]^T (+ epilogue)
// 256 thr = 4 waves. TM=128: waves 2x2 of 64x64. TM=64: waves 2x2 of 32x64.
// BK=32, LDS-staged via global_load_lds width-16 (m97 structure).
// MODE 0: +bias[col], bf16 out      (QKV q/k)
// MODE 1: +bias[row], bf16 out      (QKV v)
// MODE 2: exp(d*SCALE-12) bf16 out, + row-sum atomics into ep   (scores->P)
// MODE 3: /ep[col], f32 out         (PV, ep = row sums)
// ---------------------------------------------------------------------------
template<int MODE, int KDIM, int TM>
__device__ __forceinline__ void gemm_core(
    const unsigned short* __restrict__ A,   // pre-offset to tile row m0
    const unsigned short* __restrict__ Bm,  // pre-offset to tile row n0
    unsigned short* As, unsigned short* Bs, // [TM*32], [128*32]
    void* __restrict__ OutV, int ldo,       // pre-offset to (m0, n0)
    float* __restrict__ ep)                 // bias / rsum (pre-offset)
{
    const int t = threadIdx.x;
    const int wave = t >> 6, lane = t & 63;
    const int ll = t & 15, quad = (t >> 4) & 3;
    const int lr = lane >> 2, chunk = lane & 3;
    constexpr int MI = TM / 32;                       // 16-row m-subtiles/wave
    const int wm = (wave & 1) * (TM / 2), wn = (wave >> 1) * 64;

    const unsigned short* gA0 = A  + (size_t)(wave * (TM / 4) + lr) * KDIM + chunk * 8;
    const unsigned short* gB0 = Bm + (size_t)(wave * 32 + lr) * KDIM + chunk * 8;
    unsigned short* lA0 = As + (wave * (TM / 4)) * 32;   // wave-uniform bases
    unsigned short* lB0 = Bs + (wave * 32) * 32;

    f32x4 acc[MI][4];
#pragma unroll
    for (int i = 0; i < MI; ++i)
#pragma unroll
        for (int j = 0; j < 4; ++j) acc[i][j] = (f32x4){0.f, 0.f, 0.f, 0.f};

#pragma unroll 1
    for (int k0 = 0; k0 < KDIM; k0 += 32) {
        __syncthreads();                      // prev compute done reading LDS
        load_lds16(gA0 + k0, lA0);
        if (TM == 128) load_lds16(gA0 + (size_t)16 * KDIM + k0, lA0 + 16 * 32);
        load_lds16(gB0 + k0, lB0);
        load_lds16(gB0 + (size_t)16 * KDIM + k0, lB0 + 16 * 32);
        __syncthreads();                      // staging visible

        bf16x8 af[MI], bf[4];
#pragma unroll
        for (int mi = 0; mi < MI; ++mi)
            af[mi] = *(const bf16x8*)&As[(wm + mi * 16 + ll) * 32 + quad * 8];
#pragma unroll
        for (int ni = 0; ni < 4; ++ni)
            bf[ni] = *(const bf16x8*)&Bs[(wn + ni * 16 + ll) * 32 + quad * 8];
#pragma unroll
        for (int mi = 0; mi < MI; ++mi)
#pragma unroll
            for (int ni = 0; ni < 4; ++ni)
                acc[mi][ni] = MFMA(af[mi], bf[ni], acc[mi][ni]);
    }

    float rpart[MI][4];
    if (MODE == 2) {
#pragma unroll
        for (int mi = 0; mi < MI; ++mi)
#pragma unroll
            for (int r = 0; r < 4; ++r) rpart[mi][r] = 0.f;
    }

#pragma unroll
    for (int mi = 0; mi < MI; ++mi)
#pragma unroll
        for (int ni = 0; ni < 4; ++ni) {
            const int col = wn + ni * 16 + ll;
            float epc = 0.f;
            if (MODE == 0) epc = ep[col];
            if (MODE == 3) epc = 1.0f / ep[col];
#pragma unroll
            for (int r = 0; r < 4; ++r) {
                const int row = wm + mi * 16 + quad * 4 + r;
                float v = acc[mi][ni][r];
                if (MODE == 0)      v += epc;
                else if (MODE == 1) v += ep[row];
                else if (MODE == 2) { v = __expf(v * SCALE - 12.f); rpart[mi][r] += v; }
                else                v *= epc;
                if (MODE == 3)
                    ((float*)OutV)[(size_t)row * ldo + col] = v;
                else
                    ((unsigned short*)OutV)[(size_t)row * ldo + col] = f2bf(v);
            }
        }

    if (MODE == 2) {   // row-sum: reduce over the 16 ll-lanes, one atomic/row
#pragma unroll
        for (int mi = 0; mi < MI; ++mi)
#pragma unroll
            for (int r = 0; r < 4; ++r) {
                float s = rpart[mi][r];
                s += __shfl_xor(s, 1, 64);
                s += __shfl_xor(s, 2, 64);
                s += __shfl_xor(s, 4, 64);
                s += __shfl_xor(s, 8, 64);
                if (ll == 0) atomicAdd(ep + wm + mi * 16 + quad * 4 + r, s);
            }
    }
}

// ---------------------------------------------------------------------------
// Kernel 0a: x [B][C][L] fp32 -> xt [B][L][C] bf16 (64x64 tile, vectorized)
// ---------------------------------------------------------------------------
__global__ __launch_bounds__(256) void xpose_cvt(
    const float* __restrict__ x, unsigned short* __restrict__ xt)
{
    __shared__ float tile[64][69];
    const int b = blockIdx.z, l0 = blockIdx.x * 64, c0 = blockIdx.y * 64;
    const int t = threadIdx.x;
    const int lx = t & 15, cy = t >> 4;          // load: float4 along L
    const float* xb = x + (size_t)b * C * L;
#pragma unroll
    for (int p = 0; p < 4; ++p) {
        float4 v = *(const float4*)(xb + (size_t)(c0 + p * 16 + cy) * L + l0 + lx * 4);
        tile[p * 16 + cy][lx * 4 + 0] = v.x;
        tile[p * 16 + cy][lx * 4 + 1] = v.y;
        tile[p * 16 + cy][lx * 4 + 2] = v.z;
        tile[p * 16 + cy][lx * 4 + 3] = v.w;
    }
    __syncthreads();
    const int ocl = t & 15, ot = t >> 4;         // store: 4 bf16 (8B) along C
    unsigned short* xtb = xt + (size_t)b * L * C;
#pragma unroll
    for (int p = 0; p < 4; ++p) {
        int ol = p * 16 + ot;
        union { unsigned short h[4]; uint2 u; } pk;
#pragma unroll
        for (int i = 0; i < 4; ++i) pk.h[i] = f2bf(tile[ocl * 4 + i][ol]);
        *(uint2*)(xtb + (size_t)(l0 + ol) * C + c0 + ocl * 4) = pk.u;
    }
}

// ---------------------------------------------------------------------------
// Kernel 0b: Wq|Wk|Wv fp32 -> contiguous bf16
// ---------------------------------------------------------------------------
__global__ __launch_bounds__(256) void wcvt(
    const float* __restrict__ Wq, const float* __restrict__ Wk,
    const float* __restrict__ Wv, unsigned short* __restrict__ o)
{
    const int i = (blockIdx.x * 256 + threadIdx.x) * 4;
    const int which = i >> 18;                            // C*C = 2^18
    const int off = i & 0x3FFFF;
    const float* src = (which == 0) ? Wq : (which == 1) ? Wk : Wv;
    float4 v = *(const float4*)(src + off);
    union { unsigned short h[4]; uint2 u; } pk;
    pk.h[0] = f2bf(v.x); pk.h[1] = f2bf(v.y); pk.h[2] = f2bf(v.z); pk.h[3] = f2bf(v.w);
    *(uint2*)(o + i) = pk.u;
}

// ---------------------------------------------------------------------------
// Kernel 1: QKV projection (128x128 tiles)
// ---------------------------------------------------------------------------
__global__ __launch_bounds__(256) void qkv_gemm(
    const unsigned short* __restrict__ xt, const unsigned short* __restrict__ Wb,
    const float* __restrict__ bq, const float* __restrict__ bk,
    const float* __restrict__ bv,
    unsigned short* __restrict__ Qt, unsigned short* __restrict__ Kt,
    unsigned short* __restrict__ Vv)
{
    __shared__ unsigned short As[128 * 32], Bs[128 * 32];
    const int which = blockIdx.z >> 3, b = blockIdx.z & 7;
    const unsigned short* xtb = xt + (size_t)b * L * C;
    if (which < 2) {
        const int m0 = blockIdx.x * 128, n0 = blockIdx.y * 128;  // M=L, N=C
        const unsigned short* A  = xtb + (size_t)m0 * C;
        const unsigned short* Bm = Wb + (size_t)which * C * C + (size_t)n0 * C;
        unsigned short* Out = (which ? Kt : Qt) + (size_t)b * L * C
                              + (size_t)m0 * C + n0;
        gemm_core<0, C, 128>(A, Bm, As, Bs, Out, C,
                             const_cast<float*>((which ? bk : bq) + n0));
    } else {
        const int m0 = blockIdx.y * 128, n0 = blockIdx.x * 128;  // M=C, N=L
        const unsigned short* A  = Wb + (size_t)2 * C * C + (size_t)m0 * C;
        const unsigned short* Bm = xtb + (size_t)n0 * C;
        unsigned short* Out = Vv + (size_t)b * C * L + (size_t)m0 * L + n0;
        gemm_core<1, C, 128>(A, Bm, As, Bs, Out, L, const_cast<float*>(bv + m0));
    }
}

// ---------------------------------------------------------------------------
// Kernel 2: P = exp(Q K^T * scale - 12) + fused row-sum atomics
// ---------------------------------------------------------------------------
__global__ __launch_bounds__(256) void sc_exp(
    const unsigned short* __restrict__ Qt, const unsigned short* __restrict__ Kt,
    unsigned short* __restrict__ P, float* __restrict__ rsum,
    int hoff, int qrows)
{
    __shared__ unsigned short As[128 * 32], Bs[128 * 32];
    const int b = blockIdx.z, m0 = blockIdx.x * 128, n0 = blockIdx.y * 128;
    const unsigned short* A  = Qt + (size_t)b * L * C + (size_t)(hoff + m0) * C;
    const unsigned short* Bm = Kt + (size_t)b * L * C + (size_t)n0 * C;
    unsigned short* Out = P + (size_t)b * qrows * L + (size_t)m0 * L + n0;
    float* ep = rsum + (size_t)b * L + hoff + m0;
    gemm_core<2, C, 128>(A, Bm, As, Bs, Out, L, ep);
}

// ---------------------------------------------------------------------------
// Kernel 3: O = (V @ P^T) / rsum[col]   (64x128 tiles -> 4 blocks/CU)
// ---------------------------------------------------------------------------
__global__ __launch_bounds__(256) void pv_gemm(
    const unsigned short* __restrict__ Vv, const unsigned short* __restrict__ P,
    const float* __restrict__ rsum, float* __restrict__ out,
    int hoff, int qrows)
{
    __shared__ unsigned short As[64 * 32], Bs[128 * 32];
    const int b = blockIdx.z, m0 = blockIdx.x * 64, n0 = blockIdx.y * 128;
    const unsigned short* A  = Vv + (size_t)b * C * L + (size_t)m0 * L;
    const unsigned short* Bm = P + (size_t)b * qrows * L + (size_t)n0 * L;
    float* Out = out + (size_t)b * C * L + (size_t)m0 * L + hoff + n0;
    float* ep = const_cast<float*>(rsum) + (size_t)b * L + hoff + n0;
    gemm_core<3, L, 64>(A, Bm, As, Bs, Out, L, ep);
}

extern "C" void kernel_launch(void* const* d_in, const int* in_sizes, int n_in,
                              void* d_out, int out_size, void* d_ws, size_t ws_size,
                              hipStream_t stream) {
    const float* x  = (const float*)d_in[0];
    const float* Wq = (const float*)d_in[1];
    const float* bq = (const float*)d_in[2];
    const float* Wk = (const float*)d_in[3];
    const float* bk = (const float*)d_in[4];
    const float* Wv = (const float*)d_in[5];
    const float* bv = (const float*)d_in[6];
    float* out = (float*)d_out;

    const size_t BCL = (size_t)B * C * L;                // 8.39M elems
    const bool fullP = ws_size >= 119078912ull;          // exact full-P footprint

    unsigned short* Qt = (unsigned short*)d_ws;          // [B][L][C] bf16
    unsigned short* Kt = Qt + BCL;
    unsigned short* Vv = Kt + BCL;                       // [B][C][L]
    unsigned short *Wb, *xt, *P;
    float* rsum;
    if (fullP) {
        Wb   = Vv + BCL;                                 // 1.57 MB, live during qkv
        rsum = (float*)(Wb + (size_t)3 * C * C);         // [B][L] f32
        xt   = (unsigned short*)(rsum + (size_t)B * L);  // dead after qkv
        P    = xt;                                       // [B][L][L] bf16, aliases xt
    } else {                                             // 85.6 MB fallback
        xt   = Vv + BCL;
        P    = xt;                                       // [B][1024][L], aliases xt
        Wb   = P + (size_t)B * 1024 * L;
        rsum = (float*)(Wb + (size_t)3 * C * C);
    }

    hipMemsetAsync(rsum, 0, (size_t)B * L * 4, stream);
    xpose_cvt<<<dim3(L / 64, C / 64, B), 256, 0, stream>>>(x, xt);
    wcvt<<<dim3(3 * C * C / 1024), 256, 0, stream>>>(Wq, Wk, Wv, Wb);
    qkv_gemm<<<dim3(16, 4, 24), 256, 0, stream>>>(xt, Wb, bq, bk, bv, Qt, Kt, Vv);

    if (fullP) {
        sc_exp<<<dim3(16, 16, 8), 256, 0, stream>>>(Qt, Kt, P, rsum, 0, L);
        pv_gemm<<<dim3(8, 16, 8), 256, 0, stream>>>(Vv, P, rsum, out, 0, L);
    } else {
        for (int h = 0; h < 2; ++h) {
            sc_exp<<<dim3(8, 16, 8), 256, 0, stream>>>(Qt, Kt, P, rsum, h * 1024, 1024);
            pv_gemm<<<dim3(8, 8, 8), 256, 0, stream>>>(Vv, P, rsum, out, h * 1024, 1024);
        }
    }
}

// Round 5
// 246.832 us; speedup vs baseline: 43.2318x; 1.1613x over previous
//
#include <hip/hip_runtime.h>
#include <hip/hip_bf16.h>
#include <math.h>

#define B 8
#define C 512
#define L 2048

using bf16x8 = __bf16 __attribute__((ext_vector_type(8)));
using f32x4  = float __attribute__((ext_vector_type(4)));

#define MFMA(a, b, c) __builtin_amdgcn_mfma_f32_16x16x32_bf16((a), (b), (c), 0, 0, 0)
#define SCALE 0.044194173824159216f   /* 1/sqrt(512) */

__device__ __forceinline__ unsigned short f2bf(float f) {
    __hip_bfloat16 h = __float2bfloat16(f);   // RNE
    return *reinterpret_cast<unsigned short*>(&h);
}
// async global->LDS, 16B/lane; LDS dest = wave-uniform base + lane*16
__device__ __forceinline__ void load_lds16(const unsigned short* g, unsigned short* l) {
    __builtin_amdgcn_global_load_lds(
        (const __attribute__((address_space(1))) unsigned int*)g,
        (__attribute__((address_space(3))) unsigned int*)l, 16, 0, 0);
}

// ---------------------------------------------------------------------------
// GEMM-NT core: D[128 m][128 n] = A[128][K] * B[128][K]^T (+ epilogue)
// 256 thr = 4 waves (2x2 of 64x64), BK=32, global_load_lds staging (m97).
// MODE 0: +bias[col], bf16 out      (QKV q/k)
// MODE 1: +bias[row], bf16 out      (QKV v)
// MODE 2: exp(d*SCALE-12) bf16 out, + row-sum atomics into ep   (scores->P)
// MODE 3: /ep[col], f32 out         (PV, ep = row sums)
// ---------------------------------------------------------------------------
template<int MODE, int KDIM>
__device__ __forceinline__ void gemm_core(
    const unsigned short* __restrict__ A,   // pre-offset to tile row m0
    const unsigned short* __restrict__ Bm,  // pre-offset to tile row n0
    unsigned short* As, unsigned short* Bs, // [128*32] each
    void* __restrict__ OutV, int ldo,       // pre-offset to (m0, n0)
    float* __restrict__ ep)                 // bias / rsum (pre-offset)
{
    const int t = threadIdx.x;
    const int wave = t >> 6, lane = t & 63;
    const int ll = t & 15, quad = (t >> 4) & 3;
    const int lr = lane >> 2, chunk = lane & 3;
    const int wm = (wave & 1) * 64, wn = (wave >> 1) * 64;

    const unsigned short* gA0 = A  + (size_t)(wave * 32 + lr) * KDIM + chunk * 8;
    const unsigned short* gB0 = Bm + (size_t)(wave * 32 + lr) * KDIM + chunk * 8;
    unsigned short* lA0 = As + (wave * 32) * 32;        // wave-uniform bases
    unsigned short* lB0 = Bs + (wave * 32) * 32;

    f32x4 acc[4][4];
#pragma unroll
    for (int i = 0; i < 4; ++i)
#pragma unroll
        for (int j = 0; j < 4; ++j) acc[i][j] = (f32x4){0.f, 0.f, 0.f, 0.f};

#pragma unroll 1
    for (int k0 = 0; k0 < KDIM; k0 += 32) {
        __syncthreads();                      // prev compute done reading LDS
        load_lds16(gA0 + k0, lA0);
        load_lds16(gA0 + (size_t)16 * KDIM + k0, lA0 + 16 * 32);
        load_lds16(gB0 + k0, lB0);
        load_lds16(gB0 + (size_t)16 * KDIM + k0, lB0 + 16 * 32);
        __syncthreads();                      // staging visible

        bf16x8 af[4], bf[4];
#pragma unroll
        for (int mi = 0; mi < 4; ++mi)
            af[mi] = *(const bf16x8*)&As[(wm + mi * 16 + ll) * 32 + quad * 8];
#pragma unroll
        for (int ni = 0; ni < 4; ++ni)
            bf[ni] = *(const bf16x8*)&Bs[(wn + ni * 16 + ll) * 32 + quad * 8];
#pragma unroll
        for (int mi = 0; mi < 4; ++mi)
#pragma unroll
            for (int ni = 0; ni < 4; ++ni)
                acc[mi][ni] = MFMA(af[mi], bf[ni], acc[mi][ni]);
    }

    float rpart[4][4];
    if (MODE == 2) {
#pragma unroll
        for (int mi = 0; mi < 4; ++mi)
#pragma unroll
            for (int r = 0; r < 4; ++r) rpart[mi][r] = 0.f;
    }

#pragma unroll
    for (int mi = 0; mi < 4; ++mi)
#pragma unroll
        for (int ni = 0; ni < 4; ++ni) {
            const int col = wn + ni * 16 + ll;
            float epc = 0.f;
            if (MODE == 0) epc = ep[col];
            if (MODE == 3) epc = 1.0f / ep[col];
#pragma unroll
            for (int r = 0; r < 4; ++r) {
                const int row = wm + mi * 16 + quad * 4 + r;
                float v = acc[mi][ni][r];
                if (MODE == 0)      v += epc;
                else if (MODE == 1) v += ep[row];
                else if (MODE == 2) { v = __expf(v * SCALE - 12.f); rpart[mi][r] += v; }
                else                v *= epc;
                if (MODE == 3)
                    ((float*)OutV)[(size_t)row * ldo + col] = v;
                else
                    ((unsigned short*)OutV)[(size_t)row * ldo + col] = f2bf(v);
            }
        }

    if (MODE == 2) {   // row-sum: reduce over the 16 ll-lanes, one atomic/row
#pragma unroll
        for (int mi = 0; mi < 4; ++mi)
#pragma unroll
            for (int r = 0; r < 4; ++r) {
                float s = rpart[mi][r];
                s += __shfl_xor(s, 1, 64);
                s += __shfl_xor(s, 2, 64);
                s += __shfl_xor(s, 4, 64);
                s += __shfl_xor(s, 8, 64);
                if (ll == 0) atomicAdd(ep + wm + mi * 16 + quad * 4 + r, s);
            }
    }
}

// ---------------------------------------------------------------------------
// Kernel 0a: x [B][C][L] fp32 -> xt [B][L][C] bf16 (64x64 tile, vectorized)
// ---------------------------------------------------------------------------
__global__ __launch_bounds__(256) void xpose_cvt(
    const float* __restrict__ x, unsigned short* __restrict__ xt)
{
    __shared__ float tile[64][69];
    const int b = blockIdx.z, l0 = blockIdx.x * 64, c0 = blockIdx.y * 64;
    const int t = threadIdx.x;
    const int lx = t & 15, cy = t >> 4;          // load: float4 along L
    const float* xb = x + (size_t)b * C * L;
#pragma unroll
    for (int p = 0; p < 4; ++p) {
        float4 v = *(const float4*)(xb + (size_t)(c0 + p * 16 + cy) * L + l0 + lx * 4);
        tile[p * 16 + cy][lx * 4 + 0] = v.x;
        tile[p * 16 + cy][lx * 4 + 1] = v.y;
        tile[p * 16 + cy][lx * 4 + 2] = v.z;
        tile[p * 16 + cy][lx * 4 + 3] = v.w;
    }
    __syncthreads();
    const int ocl = t & 15, ot = t >> 4;         // store: 4 bf16 (8B) along C
    unsigned short* xtb = xt + (size_t)b * L * C;
#pragma unroll
    for (int p = 0; p < 4; ++p) {
        int ol = p * 16 + ot;
        union { unsigned short h[4]; uint2 u; } pk;
#pragma unroll
        for (int i = 0; i < 4; ++i) pk.h[i] = f2bf(tile[ocl * 4 + i][ol]);
        *(uint2*)(xtb + (size_t)(l0 + ol) * C + c0 + ocl * 4) = pk.u;
    }
}

// ---------------------------------------------------------------------------
// Kernel 0b: Wq|Wk|Wv fp32 -> contiguous bf16
// ---------------------------------------------------------------------------
__global__ __launch_bounds__(256) void wcvt(
    const float* __restrict__ Wq, const float* __restrict__ Wk,
    const float* __restrict__ Wv, unsigned short* __restrict__ o)
{
    const int i = (blockIdx.x * 256 + threadIdx.x) * 4;
    const int which = i >> 18;                            // C*C = 2^18
    const int off = i & 0x3FFFF;
    const float* src = (which == 0) ? Wq : (which == 1) ? Wk : Wv;
    float4 v = *(const float4*)(src + off);
    union { unsigned short h[4]; uint2 u; } pk;
    pk.h[0] = f2bf(v.x); pk.h[1] = f2bf(v.y); pk.h[2] = f2bf(v.z); pk.h[3] = f2bf(v.w);
    *(uint2*)(o + i) = pk.u;
}

// ---------------------------------------------------------------------------
// Kernel 1: QKV projection. 1-D grid 1536: b = id&7 (XCD), r = id>>3:
//   which = r>>6; q/k: m = t&15 (fastest), n = t>>4; v: m = t&3, n = t>>2
// ---------------------------------------------------------------------------
__global__ __launch_bounds__(256) void qkv_gemm(
    const unsigned short* __restrict__ xt, const unsigned short* __restrict__ Wb,
    const float* __restrict__ bq, const float* __restrict__ bk,
    const float* __restrict__ bv,
    unsigned short* __restrict__ Qt, unsigned short* __restrict__ Kt,
    unsigned short* __restrict__ Vv)
{
    __shared__ unsigned short As[128 * 32], Bs[128 * 32];
    const int id = blockIdx.x;
    const int b = id & 7, r = id >> 3;          // r in 0..191
    const int which = r >> 6, tt = r & 63;
    const unsigned short* xtb = xt + (size_t)b * L * C;
    if (which < 2) {
        const int m0 = (tt & 15) * 128, n0 = (tt >> 4) * 128;   // M=L, N=C
        const unsigned short* A  = xtb + (size_t)m0 * C;
        const unsigned short* Bm = Wb + (size_t)which * C * C + (size_t)n0 * C;
        unsigned short* Out = (which ? Kt : Qt) + (size_t)b * L * C
                              + (size_t)m0 * C + n0;
        gemm_core<0, C>(A, Bm, As, Bs, Out, C,
                        const_cast<float*>((which ? bk : bq) + n0));
    } else {
        const int m0 = (tt & 3) * 128, n0 = (tt >> 2) * 128;    // M=C, N=L
        const unsigned short* A  = Wb + (size_t)2 * C * C + (size_t)m0 * C;
        const unsigned short* Bm = xtb + (size_t)n0 * C;
        unsigned short* Out = Vv + (size_t)b * C * L + (size_t)m0 * L + n0;
        gemm_core<1, C>(A, Bm, As, Bs, Out, L, const_cast<float*>(bv + m0));
    }
}

// ---------------------------------------------------------------------------
// Kernel 2: P = exp(Q K^T * scale - 12) + fused row-sum atomics
// 1-D grid: b = id&7 (XCD), r = id>>3, m = r & (mtiles-1) fastest, n = rest
// ---------------------------------------------------------------------------
__global__ __launch_bounds__(256) void sc_exp(
    const unsigned short* __restrict__ Qt, const unsigned short* __restrict__ Kt,
    unsigned short* __restrict__ P, float* __restrict__ rsum,
    int hoff, int qrows, int mshift)
{
    __shared__ unsigned short As[128 * 32], Bs[128 * 32];
    const int id = blockIdx.x;
    const int b = id & 7, r = id >> 3;
    const int m0 = (r & ((1 << mshift) - 1)) * 128, n0 = (r >> mshift) * 128;
    const unsigned short* A  = Qt + (size_t)b * L * C + (size_t)(hoff + m0) * C;
    const unsigned short* Bm = Kt + (size_t)b * L * C + (size_t)n0 * C;
    unsigned short* Out = P + (size_t)b * qrows * L + (size_t)m0 * L + n0;
    float* ep = rsum + (size_t)b * L + hoff + m0;
    gemm_core<2, C>(A, Bm, As, Bs, Out, L, ep);
}

// ---------------------------------------------------------------------------
// Kernel 3: O = (V @ P^T) / rsum[col]
// 1-D grid: b = id&7 (XCD), r = id>>3, m = r&3 fastest (M=C: 4 tiles), n rest
// ---------------------------------------------------------------------------
__global__ __launch_bounds__(256) void pv_gemm(
    const unsigned short* __restrict__ Vv, const unsigned short* __restrict__ P,
    const float* __restrict__ rsum, float* __restrict__ out,
    int hoff, int qrows)
{
    __shared__ unsigned short As[128 * 32], Bs[128 * 32];
    const int id = blockIdx.x;
    const int b = id & 7, r = id >> 3;
    const int m0 = (r & 3) * 128, n0 = (r >> 2) * 128;
    const unsigned short* A  = Vv + (size_t)b * C * L + (size_t)m0 * L;
    const unsigned short* Bm = P + (size_t)b * qrows * L + (size_t)n0 * L;
    float* Out = out + (size_t)b * C * L + (size_t)m0 * L + hoff + n0;
    float* ep = const_cast<float*>(rsum) + (size_t)b * L + hoff + n0;
    gemm_core<3, L>(A, Bm, As, Bs, Out, L, ep);
}

extern "C" void kernel_launch(void* const* d_in, const int* in_sizes, int n_in,
                              void* d_out, int out_size, void* d_ws, size_t ws_size,
                              hipStream_t stream) {
    const float* x  = (const float*)d_in[0];
    const float* Wq = (const float*)d_in[1];
    const float* bq = (const float*)d_in[2];
    const float* Wk = (const float*)d_in[3];
    const float* bk = (const float*)d_in[4];
    const float* Wv = (const float*)d_in[5];
    const float* bv = (const float*)d_in[6];
    float* out = (float*)d_out;

    const size_t BCL = (size_t)B * C * L;                // 8.39M elems
    const bool fullP = ws_size >= 119078912ull;          // full-P footprint

    unsigned short* Qt = (unsigned short*)d_ws;          // [B][L][C] bf16
    unsigned short* Kt = Qt + BCL;
    unsigned short* Vv = Kt + BCL;                       // [B][C][L]
    unsigned short *Wb, *xt, *P;
    float* rsum;
    if (fullP) {
        Wb   = Vv + BCL;                                 // 1.57 MB, live during qkv
        rsum = (float*)(Wb + (size_t)3 * C * C);         // [B][L] f32
        xt   = (unsigned short*)(rsum + (size_t)B * L);  // dead after qkv
        P    = xt;                                       // [B][L][L] bf16, aliases xt
    } else {                                             // 85.6 MB fallback
        xt   = Vv + BCL;
        P    = xt;                                       // [B][1024][L], aliases xt
        Wb   = P + (size_t)B * 1024 * L;
        rsum = (float*)(Wb + (size_t)3 * C * C);
    }

    hipMemsetAsync(rsum, 0, (size_t)B * L * 4, stream);
    xpose_cvt<<<dim3(L / 64, C / 64, B), 256, 0, stream>>>(x, xt);
    wcvt<<<dim3(3 * C * C / 1024), 256, 0, stream>>>(Wq, Wk, Wv, Wb);
    qkv_gemm<<<dim3(1536), 256, 0, stream>>>(xt, Wb, bq, bk, bv, Qt, Kt, Vv);

    if (fullP) {
        sc_exp<<<dim3(2048), 256, 0, stream>>>(Qt, Kt, P, rsum, 0, L, 4);
        pv_gemm<<<dim3(512), 256, 0, stream>>>(Vv, P, rsum, out, 0, L);
    } else {
        for (int h = 0; h < 2; ++h) {
            sc_exp<<<dim3(1024), 256, 0, stream>>>(Qt, Kt, P, rsum, h * 1024, 1024, 3);
            pv_gemm<<<dim3(256), 256, 0, stream>>>(Vv, P, rsum, out, h * 1024, 1024);
        }
    }
}